// Round 1
// baseline (280.083 us; speedup 1.0000x reference)
//
#include <hip/hip_runtime.h>

// Self-attention block (non-local): B=8, C=256, H=W=64 -> N=4096, dk=64.
// out = x + gamma * softmax((Wq x)^T (Wk x) / 8) applied to (Wv x).
// Pipeline: prep (weights->bf16, fold log2e/8 into Wq) -> proj (MFMA GEMM,
// in-LDS transpose of x) -> flash (max-free online softmax attention,
// swapped-QK + in-register P fragments, fused residual epilogue).

typedef __attribute__((ext_vector_type(8)))  short short8;
typedef __attribute__((ext_vector_type(4)))  short short4v;
typedef __attribute__((ext_vector_type(16))) float f32x16;
typedef __attribute__((ext_vector_type(4)))  float f32x4;

#define B_   8
#define C_   256
#define N_   4096
#define DK_  64
// log2(e) / sqrt(dk) = 1.4426950408889634 / 8
#define QSCL 0.18033688011112043f

#if defined(__has_builtin)
#if __has_builtin(__builtin_amdgcn_exp2f)
#define EXP2F(x) __builtin_amdgcn_exp2f(x)
#else
#define EXP2F(x) exp2f(x)
#endif
#else
#define EXP2F(x) exp2f(x)
#endif

// float -> bf16 bits, round-to-nearest-even (inputs are finite; no NaN path)
__device__ __forceinline__ unsigned short bfb(float f) {
  unsigned u = __builtin_bit_cast(unsigned, f);
  unsigned r = (u + 0x7fffu + ((u >> 16) & 1u)) >> 16;
  return (unsigned short)r;
}

__device__ __forceinline__ unsigned pk2(float a, float b) {
  return ((unsigned)bfb(b) << 16) | (unsigned)bfb(a);
}

// ---------------------------------------------------------------------------
// Kernel 1: weight prep.  W'[384][256] bf16 = [Wq*QSCL ; Wk ; Wv], bias'[384].
// ---------------------------------------------------------------------------
__global__ void prep_kernel(const float* __restrict__ Wq, const float* __restrict__ bq,
                            const float* __restrict__ Wk, const float* __restrict__ bk,
                            const float* __restrict__ Wv, const float* __restrict__ bv,
                            unsigned short* __restrict__ Wc, float* __restrict__ biasc) {
  int idx = blockIdx.x * 256 + threadIdx.x;
  if (idx < 384 * 256) {
    int ch = idx >> 8, c = idx & 255;
    float v;
    if (ch < 64)       v = Wq[ch * 256 + c] * QSCL;
    else if (ch < 128) v = Wk[(ch - 64) * 256 + c];
    else               v = Wv[(ch - 128) * 256 + c];
    Wc[idx] = bfb(v);
  }
  if (idx < 384) {
    float bb;
    if (idx < 64)       bb = bq[idx] * QSCL;
    else if (idx < 128) bb = bk[idx - 64];
    else                bb = bv[idx - 128];
    biasc[idx] = bb;
  }
}

// ---------------------------------------------------------------------------
// Kernel 2: projections.  Per (batch, 64-row n-block): stage x[256c][64n]
// transposed into LDS as bf16 (XOR-swizzled), then OUT[n][ch] = Xt * W'^T via
// 32x32x16 bf16 MFMA.  Outputs: Qt,Kt [B][N][64] (n-major), V [B][C][N].
// ---------------------------------------------------------------------------
__global__ __launch_bounds__(256, 2) void proj_kernel(
    const float* __restrict__ x, const unsigned short* __restrict__ Wc,
    const float* __restrict__ biasc, unsigned short* __restrict__ Qt,
    unsigned short* __restrict__ Kt, unsigned short* __restrict__ V) {
  __shared__ unsigned short XT[64 * 256];  // [n][c] bf16, swizzled, 32 KiB
  const int tid = threadIdx.x;
  const int b = blockIdx.y;
  const int n0 = blockIdx.x * 64;

  // stage: x[b][c][n0+0..63] fp32 -> XT[n][c] bf16 (transpose), swizzle:
  // ushort idx = n*256 + (((c>>3) ^ (n&15))<<3) + (c&7)
  {
    const f32x4* x4 = (const f32x4*)(x + ((size_t)b * C_) * N_ + n0);
    int c = tid >> 4;                  // 0..15 (+16 per pass)
    const int nl = (tid & 15) << 2;    // 0,4,...,60
#pragma unroll
    for (int p = 0; p < 16; ++p, c += 16) {
      f32x4 v = x4[(size_t)c * (N_ / 4) + (nl >> 2)];
#pragma unroll
      for (int i = 0; i < 4; ++i) {
        int n = nl + i;
        XT[n * 256 + ((((c >> 3) ^ (n & 15)) << 3) | (c & 7))] = bfb(v[i]);
      }
    }
  }
  __syncthreads();

  const int lane = tid & 63, li = lane & 31, hi = lane >> 5;
  const int w = tid >> 6;
  const int ch0 = 96 * w;  // this wave's 96 output channels (3 x 32)

  f32x16 acc[2][3];
#pragma unroll
  for (int mt = 0; mt < 2; ++mt)
#pragma unroll
    for (int j = 0; j < 3; ++j)
#pragma unroll
      for (int r = 0; r < 16; ++r) acc[mt][j][r] = 0.f;

  const short8* Wc8 = (const short8*)Wc;
#pragma unroll
  for (int ks = 0; ks < 16; ++ks) {
    // A-frags: lane holds Xt[n=32*mt+li][c=16*ks+8*hi .. +8]
    int chunk = 2 * ks + hi;
    short8 a0 = *(const short8*)&XT[(li) * 256 + ((chunk ^ (li & 15)) << 3)];
    short8 a1 = *(const short8*)&XT[(32 + li) * 256 + ((chunk ^ (li & 15)) << 3)];
#pragma unroll
    for (int j = 0; j < 3; ++j) {
      short8 bf = Wc8[(size_t)(ch0 + 32 * j + li) * 32 + chunk];
      acc[0][j] = __builtin_amdgcn_mfma_f32_32x32x16_bf16(a0, bf, acc[0][j], 0, 0, 0);
      acc[1][j] = __builtin_amdgcn_mfma_f32_32x32x16_bf16(a1, bf, acc[1][j], 0, 0, 0);
    }
  }

  // epilogue: D[row=n][col=ch], row = (r&3)+8*(r>>2)+4*hi + 32*mt, col = li
#pragma unroll
  for (int j = 0; j < 3; ++j) {
    const int chb = ch0 + 32 * j;  // wave-uniform 32-block, never straddles Q/K/V
    const int ch = chb + li;
    const float bias = biasc[ch];
#pragma unroll
    for (int mt = 0; mt < 2; ++mt) {
      if (chb < 64) {
#pragma unroll
        for (int r = 0; r < 16; ++r) {
          int n = n0 + 32 * mt + (r & 3) + 8 * (r >> 2) + 4 * hi;
          Qt[((size_t)(b * N_ + n) << 6) + ch] = bfb(acc[mt][j][r] + bias);
        }
      } else if (chb < 128) {
#pragma unroll
        for (int r = 0; r < 16; ++r) {
          int n = n0 + 32 * mt + (r & 3) + 8 * (r >> 2) + 4 * hi;
          Kt[((size_t)(b * N_ + n) << 6) + (ch - 64)] = bfb(acc[mt][j][r] + bias);
        }
      } else {
        const int cv = ch - 128;
#pragma unroll
        for (int q = 0; q < 4; ++q) {  // 4 consecutive n per 8B store
          short4v pk;
#pragma unroll
          for (int i = 0; i < 4; ++i) pk[i] = (short)bfb(acc[mt][j][4 * q + i] + bias);
          int n = n0 + 32 * mt + 8 * q + 4 * hi;
          *(short4v*)&V[(size_t)(b * C_ + cv) * N_ + n] = pk;
        }
      }
    }
  }
}

// ---------------------------------------------------------------------------
// Kernel 3: attention.  Grid (64 m-blocks, 8 batches) x 256 threads.
// 4 independent waves per WG: wave w owns m-rows [m0, m0+64) and channel
// slice [64w, 64w+64).  Max-free online softmax: P = exp2(S*log2e) (scale
// folded into Wq), den accumulated, divide at end.  Swapped QK^T puts P's
// q-row in lane (m = lane&31); cvt-pk + shfl_xor(32) builds PV A-frags
// in-register (no LDS, no barriers in the K/V loop).
// ---------------------------------------------------------------------------
__global__ __launch_bounds__(256, 2) void flash_kernel(
    const unsigned short* __restrict__ Qt, const unsigned short* __restrict__ Kt,
    const unsigned short* __restrict__ V, const float* __restrict__ x,
    const float* __restrict__ gamma, float* __restrict__ out) {
  __shared__ float TB[4][32 * 33];  // per-wave padded transpose tile
  const int tid = threadIdx.x;
  const int lane = tid & 63, li = lane & 31, hi = lane >> 5;
  const int w = tid >> 6;
  const int b = blockIdx.y;
  const int m0 = blockIdx.x * 64;

  const short8* Qt8 = (const short8*)Qt;
  const short8* Kt8 = (const short8*)Kt;
  const short8* V8 = (const short8*)V;

  // Q B-frags: lane holds Qt[m0+32*mt+li][16*ks+8*hi .. +8]
  short8 qb[2][4];
#pragma unroll
  for (int mt = 0; mt < 2; ++mt)
#pragma unroll
    for (int ks = 0; ks < 4; ++ks)
      qb[mt][ks] = Qt8[((size_t)b * N_ + m0 + 32 * mt + li) * 8 + 2 * ks + hi];

  f32x16 acc[2][2];
#pragma unroll
  for (int mt = 0; mt < 2; ++mt)
#pragma unroll
    for (int ct = 0; ct < 2; ++ct)
#pragma unroll
      for (int r = 0; r < 16; ++r) acc[mt][ct][r] = 0.f;
  float den[2] = {0.f, 0.f};

  for (int kv = 0; kv < N_; kv += 64) {
    short8 pa[2][4];  // PV A-frags: P[m=li][n = kv + 16*ks2 + 8*hi + j]
#pragma unroll
    for (int nt = 0; nt < 2; ++nt) {
      short8 kf[4];
#pragma unroll
      for (int ks = 0; ks < 4; ++ks)
        kf[ks] = Kt8[((size_t)b * N_ + kv + 32 * nt + li) * 8 + 2 * ks + hi];
#pragma unroll
      for (int mt = 0; mt < 2; ++mt) {
        f32x16 st;
#pragma unroll
        for (int r = 0; r < 16; ++r) st[r] = 0.f;
#pragma unroll
        for (int ks = 0; ks < 4; ++ks)
          st = __builtin_amdgcn_mfma_f32_32x32x16_bf16(kf[ks], qb[mt][ks], st, 0, 0, 0);
        // St[n][m]: lane holds n_local = (r&3)+8*(r>>2)+4*hi, m = li
        float e[16];
        float ds = 0.f;
#pragma unroll
        for (int r = 0; r < 16; ++r) {
          e[r] = EXP2F(st[r]);
          ds += e[r];
        }
        den[mt] += ds;
        // pack: frag ks'=2*nt+h needs n_local = 16*h + 8*hi + j (j=0..7)
#pragma unroll
        for (int h = 0; h < 2; ++h) {
          unsigned X0 = pk2(e[8 * h + 0], e[8 * h + 1]);
          unsigned X1 = pk2(e[8 * h + 2], e[8 * h + 3]);
          unsigned Y0 = pk2(e[8 * h + 4], e[8 * h + 5]);
          unsigned Y1 = pk2(e[8 * h + 6], e[8 * h + 7]);
          unsigned sX0 = (unsigned)__shfl_xor((int)X0, 32);
          unsigned sX1 = (unsigned)__shfl_xor((int)X1, 32);
          unsigned sY0 = (unsigned)__shfl_xor((int)Y0, 32);
          unsigned sY1 = (unsigned)__shfl_xor((int)Y1, 32);
          union { unsigned u[4]; short8 s; } uu;
          uu.u[0] = hi ? sY0 : X0;
          uu.u[1] = hi ? sY1 : X1;
          uu.u[2] = hi ? Y0 : sX0;
          uu.u[3] = hi ? Y1 : sX1;
          pa[mt][2 * nt + h] = uu.s;
        }
      }
    }
    // PV: O[m][c] += P[m][n] * V[c][n]
#pragma unroll
    for (int ct = 0; ct < 2; ++ct) {
      const size_t vrow = ((size_t)b * C_ + 64 * w + 32 * ct + li) * (N_ / 8);
#pragma unroll
      for (int k2 = 0; k2 < 4; ++k2) {
        short8 vf = V8[vrow + (kv >> 3) + 2 * k2 + hi];
        acc[0][ct] = __builtin_amdgcn_mfma_f32_32x32x16_bf16(pa[0][k2], vf, acc[0][ct], 0, 0, 0);
        acc[1][ct] = __builtin_amdgcn_mfma_f32_32x32x16_bf16(pa[1][k2], vf, acc[1][ct], 0, 0, 0);
      }
    }
  }

  // epilogue: normalize, transpose 32x32 tiles via LDS, out = x + g*o
  const float g = gamma[0];
#pragma unroll
  for (int mt = 0; mt < 2; ++mt) {
    float dfull = den[mt] + __shfl_xor(den[mt], 32);
    float inv = 1.0f / dfull;
    float idn[16];
#pragma unroll
    for (int r = 0; r < 16; ++r)
      idn[r] = __shfl(inv, (r & 3) + 8 * (r >> 2) + 4 * hi);
#pragma unroll
    for (int ct = 0; ct < 2; ++ct) {
#pragma unroll
      for (int r = 0; r < 16; ++r) {
        int mrel = (r & 3) + 8 * (r >> 2) + 4 * hi;
        TB[w][mrel * 33 + li] = acc[mt][ct][r] * idn[r];
      }
      __builtin_amdgcn_s_waitcnt(0);  // lgkmcnt(0): LDS writes visible in-wave
#pragma unroll
      for (int p = 0; p < 4; ++p) {
        int cl = (lane >> 3) + 8 * p;   // 0..31 c within tile
        int mc = (lane & 7) * 4;        // 0..28 m chunk
        f32x4 o;
#pragma unroll
        for (int i = 0; i < 4; ++i) o[i] = TB[w][(mc + i) * 33 + cl];
        size_t off = ((size_t)b * C_ + 64 * w + 32 * ct + cl) * N_ + m0 + 32 * mt + mc;
        f32x4 xv = *(const f32x4*)(x + off);
#pragma unroll
        for (int i = 0; i < 4; ++i) o[i] = xv[i] + g * o[i];
        *(f32x4*)(out + off) = o;
      }
      __builtin_amdgcn_s_waitcnt(0);  // drain reads before next tile overwrites
    }
  }
}

// ---------------------------------------------------------------------------
extern "C" void kernel_launch(void* const* d_in, const int* in_sizes, int n_in,
                              void* d_out, int out_size, void* d_ws, size_t ws_size,
                              hipStream_t stream) {
  const float* x = (const float*)d_in[0];
  const float* Wq = (const float*)d_in[1];
  const float* bq = (const float*)d_in[2];
  const float* Wk = (const float*)d_in[3];
  const float* bk = (const float*)d_in[4];
  const float* Wv = (const float*)d_in[5];
  const float* bv = (const float*)d_in[6];
  const float* gamma = (const float*)d_in[7];
  float* out = (float*)d_out;

  char* ws = (char*)d_ws;
  unsigned short* Wc = (unsigned short*)(ws);                    // 196608 B
  float* biasc = (float*)(ws + 196608);                          // 1536 B
  unsigned short* Qt = (unsigned short*)(ws + 198144);           // 4 MiB
  unsigned short* Kt = (unsigned short*)(ws + 198144 + 4194304); // 4 MiB
  unsigned short* Vv = (unsigned short*)(ws + 198144 + 8388608); // 16 MiB
  // total ws use: ~25.4 MB

  prep_kernel<<<384, 256, 0, stream>>>(Wq, bq, Wk, bk, Wv, bv, Wc, biasc);
  proj_kernel<<<dim3(64, 8), 256, 0, stream>>>(x, Wc, biasc, Qt, Kt, Vv);
  flash_kernel<<<dim3(64, 8), 256, 0, stream>>>(Qt, Kt, Vv, x, gamma, out);
}